// Round 2
// baseline (784.104 us; speedup 1.0000x reference)
//
#include <hip/hip_runtime.h>
#include <math.h>

#define BB 8
#define HH 384
#define WW 384
#define CC 3
#define NPAR 6
#define DEL 10
#define MAXIT 12
#define NTILES 128
#define HWPIX (HH*WW)           // 147456
#define TILE_ (HWPIX/NTILES)    // 1152 = 3 rows
#define NACC 24
#define BLK 512

typedef float vf4 __attribute__((ext_vector_type(4)));
typedef vf4 uvf4 __attribute__((aligned(4)));   // 4B-aligned vec4 load (HW allows dword-aligned dwordx4)

__device__ __forceinline__ vf4 ldv4(const float* p) { return *(const uvf4*)p; }

__device__ __forceinline__ float cubicw(float s) {
    s = fabsf(s);
    float s2 = s * s, s3 = s2 * s;
    float w1 = 1.5f * s3 - 2.5f * s2 + 1.0f;
    float w2 = -0.5f * s3 + 2.5f * s2 - 4.0f * s + 2.0f;
    return (s <= 1.0f) ? w1 : ((s < 2.0f) ? w2 : 0.0f);
}

// bicubic sample of 3 channels at (xg,yg), clip-to-edge, Keys a=-0.5.
// Fast path (no clipping): 12 dwordx4 loads instead of 48 scalar loads.
__device__ __forceinline__ void bicubic3(const float* __restrict__ Ib, double xg, double yg, float Iw[3]) {
    double fx = floor(xg), fy = floor(yg);
    float tx = (float)(xg - fx), ty = (float)(yg - fy);
    int xi = (int)fx;
    int yi = (int)fy;
    float wx[4], wyv[4];
#pragma unroll
    for (int k = 0; k < 4; k++) {
        wx[k]  = cubicw(tx - (float)(k - 1));
        wyv[k] = cubicw(ty - (float)(k - 1));
    }
    Iw[0] = 0.f; Iw[1] = 0.f; Iw[2] = 0.f;
    if (xi >= 1 && xi <= WW - 3 && yi >= 1 && yi <= HH - 3) {
        const float* base = Ib + (yi - 1) * (WW * CC) + (xi - 1) * CC;
#pragma unroll
        for (int j = 0; j < 4; j++) {
            const float* r = base + j * (WW * CC);
            vf4 v0 = ldv4(r), v1 = ldv4(r + 4), v2 = ldv4(r + 8);
            // identical fma order to the slow path (k = 0..3)
            float r0 = fmaf(wx[0], v0.x, 0.f); r0 = fmaf(wx[1], v0.w, r0); r0 = fmaf(wx[2], v1.z, r0); r0 = fmaf(wx[3], v2.y, r0);
            float r1 = fmaf(wx[0], v0.y, 0.f); r1 = fmaf(wx[1], v1.x, r1); r1 = fmaf(wx[2], v1.w, r1); r1 = fmaf(wx[3], v2.z, r1);
            float r2 = fmaf(wx[0], v0.z, 0.f); r2 = fmaf(wx[1], v1.y, r2); r2 = fmaf(wx[2], v2.x, r2); r2 = fmaf(wx[3], v2.w, r2);
            Iw[0] = fmaf(wyv[j], r0, Iw[0]);
            Iw[1] = fmaf(wyv[j], r1, Iw[1]);
            Iw[2] = fmaf(wyv[j], r2, Iw[2]);
        }
    } else {
        int xx[4], yy[4];
#pragma unroll
        for (int k = 0; k < 4; k++) {
            xx[k] = min(max(xi + k - 1, 0), WW - 1);
            yy[k] = min(max(yi + k - 1, 0), HH - 1);
        }
#pragma unroll
        for (int j = 0; j < 4; j++) {
            const float* row = Ib + yy[j] * (WW * CC);
            float r0 = 0.f, r1 = 0.f, r2 = 0.f;
#pragma unroll
            for (int k = 0; k < 4; k++) {
                const float* q = row + xx[k] * CC;
                r0 = fmaf(wx[k], q[0], r0);
                r1 = fmaf(wx[k], q[1], r1);
                r2 = fmaf(wx[k], q[2], r2);
            }
            Iw[0] = fmaf(wyv[j], r0, Iw[0]);
            Iw[1] = fmaf(wyv[j], r1, Iw[1]);
            Iw[2] = fmaf(wyv[j], r2, Iw[2]);
        }
    }
}

extern "C" __global__ void k_init(const float* __restrict__ p0, double* __restrict__ p_store,
                                  int* __restrict__ done0) {
    int tid = threadIdx.x;
    if (tid < BB * NPAR) p_store[tid] = (double)p0[tid];
    if (tid < BB) done0[tid] = 0;
}

extern "C" __global__ __launch_bounds__(BLK)
void k_warp_reduce(const float* __restrict__ I1, const float* __restrict__ I2,
                   const double* __restrict__ p_cur, const int* __restrict__ done_cur,
                   double* __restrict__ partials) {
    const int b = blockIdx.y;
    const int tile = blockIdx.x;
    const int tid = threadIdx.x;
    if (done_cur[b]) return;  // frozen batch: solve ignores stale partials

    // this tile = rows [3*tile, 3*tile+2]
    const int r0 = 3 * tile;
    if (r0 + 2 < DEL || r0 > HH - 1 - DEL) {
        // fully outside valid1: partials must still be zeroed for the solve's sum
        if (tid < NACC) partials[((size_t)b * NTILES + tile) * NACC + tid] = 0.0;
        return;
    }

    const double* p = p_cur + b * NPAR;
    const double M00 = 1.0 + p[2], M01 = p[3], M02 = p[0];
    const double M10 = p[4], M11 = 1.0 + p[5], M12 = p[1];
    const float* I1b = I1 + (size_t)b * HWPIX * CC;
    const float* I2b = I2 + (size_t)b * HWPIX * CC;

    double acc[NACC];
#pragma unroll
    for (int i = 0; i < NACC; i++) acc[i] = 0.0;

    const int pend = (tile + 1) * TILE_;
    for (int pix = tile * TILE_ + tid; pix < pend; pix += BLK) {
        const int y = pix / WW;
        const int x = pix - y * WW;
        if (x < DEL || x >= WW - DEL || y < DEL || y >= HH - DEL) continue;  // valid1
        const double xg = M00 * (double)x + M01 * (double)y + M02;
        const double yg = M10 * (double)x + M11 * (double)y + M12;
        const double gx = rint(xg), gy = rint(yg);  // half-to-even like jnp.round
        if (!(gx >= (double)DEL && gx <= (double)(WW - DEL) &&
              gy >= (double)DEL && gy <= (double)(HH - DEL))) continue;      // wmask

        float Iw[3];
        bicubic3(I2b, xg, yg, Iw);

        // I1 neighborhood: x,y in [10,373] -> all vector loads in-bounds
        const float* c = I1b + pix * CC;
        vf4 u0 = ldv4(c - 3);          // cl0 cl1 cl2 c0
        vf4 u1 = ldv4(c + 1);          // c1 c2 cr0 cr1
        float cr2 = c[5];
        vf4 uu = ldv4(c - WW * CC);    // cu0 cu1 cu2 junk
        vf4 ud = ldv4(c + WW * CC);    // cd0 cd1 cd2 junk

        const float cl[3] = {u0.x, u0.y, u0.z};
        const float cv[3] = {u0.w, u1.x, u1.y};
        const float cr[3] = {u1.z, u1.w, cr2};
        const float cu[3] = {uu.x, uu.y, uu.z};
        const float cd[3] = {ud.x, ud.y, ud.z};

        float Af = 0.f, Bf = 0.f, Cf = 0.f, T0f = 0.f, T1f = 0.f;
#pragma unroll
        for (int ch = 0; ch < 3; ch++) {
            const float Ix = (cr[ch] - cl[ch]) * 0.5f;
            const float Iy = (cd[ch] - cu[ch]) * 0.5f;
            const float d = Iw[ch] - cv[ch];
            const float u = d * 20.0f;                    // DI/LAM
            const float w = 1.0f / sqrtf(fmaf(u, u, 1.0f));
            const float wd = w * d;
            T0f = fmaf(Ix, wd, T0f);
            T1f = fmaf(Iy, wd, T1f);
            const float wIx = w * Ix;
            Af = fmaf(wIx, Ix, Af);
            Bf = fmaf(wIx, Iy, Bf);
            Cf = fmaf(w * Iy, Iy, Cf);
        }
        const double X = (double)x, Y = (double)y;
        const double XX_ = X * X, XY_ = X * Y, YY_ = Y * Y;
        const double T0 = (double)T0f, T1 = (double)T1f;
        const double A = (double)Af, Bd = (double)Bf, Cd = (double)Cf;
        acc[0] += T0;           acc[1] = fma(T0, X, acc[1]);   acc[2] = fma(T0, Y, acc[2]);
        acc[3] += T1;           acc[4] = fma(T1, X, acc[4]);   acc[5] = fma(T1, Y, acc[5]);
        acc[6] += A;            acc[7] = fma(A, X, acc[7]);    acc[8] = fma(A, Y, acc[8]);
        acc[9] = fma(A, XX_, acc[9]);   acc[10] = fma(A, XY_, acc[10]);  acc[11] = fma(A, YY_, acc[11]);
        acc[12] += Bd;          acc[13] = fma(Bd, X, acc[13]); acc[14] = fma(Bd, Y, acc[14]);
        acc[15] = fma(Bd, XX_, acc[15]); acc[16] = fma(Bd, XY_, acc[16]); acc[17] = fma(Bd, YY_, acc[17]);
        acc[18] += Cd;          acc[19] = fma(Cd, X, acc[19]); acc[20] = fma(Cd, Y, acc[20]);
        acc[21] = fma(Cd, XX_, acc[21]); acc[22] = fma(Cd, XY_, acc[22]); acc[23] = fma(Cd, YY_, acc[23]);
    }

    // wave shuffle reduce (64 lanes), then cross-wave via LDS — deterministic
#pragma unroll
    for (int a = 0; a < NACC; a++) {
        double v = acc[a];
#pragma unroll
        for (int off = 32; off >= 1; off >>= 1) v += __shfl_down(v, off, 64);
        acc[a] = v;
    }
    __shared__ double wsum[BLK / 64][NACC];
    const int lane = tid & 63, wid = tid >> 6;
    if (lane == 0) {
#pragma unroll
        for (int a = 0; a < NACC; a++) wsum[wid][a] = acc[a];
    }
    __syncthreads();
    if (tid < NACC) {
        double s = 0.0;
#pragma unroll
        for (int w = 0; w < BLK / 64; w++) s += wsum[w][tid];
        partials[((size_t)b * NTILES + tile) * NACC + tid] = s;
    }
}

extern "C" __global__ __launch_bounds__(BLK)
void k_solve(const double* __restrict__ partials, const double* __restrict__ p_in,
             const int* __restrict__ done_in, double* __restrict__ p_out,
             int* __restrict__ done_out) {
    __shared__ double part2[BB * NACC][2];
    __shared__ double S[BB][NACC];
    const int tid = threadIdx.x;
    // 2 threads per (b,a) pair, each sums half the tiles
    const int pr = tid >> 1, j = tid & 1;
    if (pr < BB * NACC) {
        const int b = pr / NACC, a = pr - b * NACC;
        double s = 0.0;
        const int t0 = j * (NTILES / 2), t1 = t0 + NTILES / 2;
        for (int t = t0; t < t1; t++) s += partials[((size_t)b * NTILES + t) * NACC + a];
        part2[pr][j] = s;
    }
    __syncthreads();
    if (tid < BB * NACC) {
        const int b = tid / NACC, a = tid - b * NACC;
        S[b][a] = part2[tid][0] + part2[tid][1];
    }
    __syncthreads();
    if (tid >= BB) return;
    const int b = tid;
    if (done_in[b]) {
        done_out[b] = 1;
        for (int i = 0; i < NPAR; i++) p_out[b * NPAR + i] = p_in[b * NPAR + i];
        return;
    }
    const double* Sb = S[b];
    // bvec: DIJ ordering [Ix, Iy, IxX, IxY, IyX, IyY]
    double bv[6] = {Sb[0], Sb[3], Sb[1], Sb[2], Sb[4], Sb[5]};
    double Hm[6][6];
    Hm[0][0] = Sb[6];  Hm[0][1] = Sb[12]; Hm[0][2] = Sb[7];  Hm[0][3] = Sb[8];  Hm[0][4] = Sb[13]; Hm[0][5] = Sb[14];
    Hm[1][1] = Sb[18]; Hm[1][2] = Sb[13]; Hm[1][3] = Sb[14]; Hm[1][4] = Sb[19]; Hm[1][5] = Sb[20];
    Hm[2][2] = Sb[9];  Hm[2][3] = Sb[10]; Hm[2][4] = Sb[15]; Hm[2][5] = Sb[16];
    Hm[3][3] = Sb[11]; Hm[3][4] = Sb[16]; Hm[3][5] = Sb[17];
    Hm[4][4] = Sb[21]; Hm[4][5] = Sb[22];
    Hm[5][5] = Sb[23];
    for (int i = 0; i < 6; i++)
        for (int jj = 0; jj < i; jj++) Hm[i][jj] = Hm[jj][i];
    for (int i = 0; i < 6; i++) Hm[i][i] += 1e-6;

    // 6x6 Gaussian elimination with partial pivoting (fp64)
    double Aa[6][7];
    for (int i = 0; i < 6; i++) {
        for (int jj = 0; jj < 6; jj++) Aa[i][jj] = Hm[i][jj];
        Aa[i][6] = bv[i];
    }
    for (int k = 0; k < 6; k++) {
        int piv = k;
        double mx = fabs(Aa[k][k]);
        for (int r = k + 1; r < 6; r++) {
            double v = fabs(Aa[r][k]);
            if (v > mx) { mx = v; piv = r; }
        }
        if (piv != k)
            for (int jj = k; jj < 7; jj++) { double t = Aa[k][jj]; Aa[k][jj] = Aa[piv][jj]; Aa[piv][jj] = t; }
        const double inv = 1.0 / Aa[k][k];
        for (int r = k + 1; r < 6; r++) {
            const double f = Aa[r][k] * inv;
            for (int jj = k; jj < 7; jj++) Aa[r][jj] -= f * Aa[k][jj];
        }
    }
    double dp[6];
    for (int i = 5; i >= 0; i--) {
        double s = Aa[i][6];
        for (int jj = i + 1; jj < 6; jj++) s -= Aa[i][jj] * dp[jj];
        dp[i] = s / Aa[i][i];
    }
    const double nrm = sqrt(dp[0]*dp[0] + dp[1]*dp[1] + dp[2]*dp[2] + dp[3]*dp[3] + dp[4]*dp[4] + dp[5]*dp[5]);
    const int conv = (nrm < 1e-3) ? 1 : 0;

    // Mn = M(p) @ inv(M(dp));  affine 3x3, bottom row [0,0,1]
    const double* pc = p_in + b * NPAR;
    const double m00 = 1.0 + pc[2], m01 = pc[3], m02 = pc[0];
    const double m10 = pc[4], m11 = 1.0 + pc[5], m12 = pc[1];
    const double q00 = 1.0 + dp[2], q01 = dp[3], q02 = dp[0];
    const double q10 = dp[4], q11 = 1.0 + dp[5], q12 = dp[1];
    const double det = q00 * q11 - q01 * q10;
    const double i00 = q11 / det, i01 = -q01 / det;
    const double i10 = -q10 / det, i11 = q00 / det;
    const double it0 = -(i00 * q02 + i01 * q12);
    const double it1 = -(i10 * q02 + i11 * q12);
    const double n00 = m00 * i00 + m01 * i10;
    const double n01 = m00 * i01 + m01 * i11;
    const double n02 = m00 * it0 + m01 * it1 + m02;
    const double n10 = m10 * i00 + m11 * i10;
    const double n11 = m10 * i01 + m11 * i11;
    const double n12 = m10 * it0 + m11 * it1 + m12;
    p_out[b * NPAR + 0] = n02;
    p_out[b * NPAR + 1] = n12;
    p_out[b * NPAR + 2] = n00 - 1.0;
    p_out[b * NPAR + 3] = n01;
    p_out[b * NPAR + 4] = n10;
    p_out[b * NPAR + 5] = n11 - 1.0;
    done_out[b] = conv;
}

extern "C" __global__ __launch_bounds__(BLK)
void k_final_map(const float* __restrict__ I1, const float* __restrict__ I2,
                 const double* __restrict__ p_fin, float* __restrict__ DI_out,
                 float* __restrict__ Iw_out, double* __restrict__ fpart) {
    const int b = blockIdx.y;
    const int tile = blockIdx.x;
    const int tid = threadIdx.x;
    const double* p = p_fin + b * NPAR;
    const double M00 = 1.0 + p[2], M01 = p[3], M02 = p[0];
    const double M10 = p[4], M11 = 1.0 + p[5], M12 = p[1];
    const float* I1b = I1 + (size_t)b * HWPIX * CC;
    const float* I2b = I2 + (size_t)b * HWPIX * CC;
    float* DIb = DI_out + (size_t)b * HWPIX * CC;
    float* Iwb = Iw_out + (size_t)b * HWPIX * CC;

    double rho_s = 0.0, cnt_s = 0.0;
    const int pend = (tile + 1) * TILE_;
    for (int pix = tile * TILE_ + tid; pix < pend; pix += BLK) {
        const int y = pix / WW;
        const int x = pix - y * WW;
        const double xg = M00 * (double)x + M01 * (double)y + M02;
        const double yg = M10 * (double)x + M11 * (double)y + M12;
        float Iw[3];
        bicubic3(I2b, xg, yg, Iw);   // Iw written unmasked, all pixels
        Iwb[pix * CC + 0] = Iw[0];
        Iwb[pix * CC + 1] = Iw[1];
        Iwb[pix * CC + 2] = Iw[2];

        const bool v1 = (x >= DEL) && (x < WW - DEL) && (y >= DEL) && (y < HH - DEL);
        const double gx = rint(xg), gy = rint(yg);
        const bool wm = (gx >= (double)DEL && gx <= (double)(WW - DEL) &&
                         gy >= (double)DEL && gy <= (double)(HH - DEL));
        const bool m = v1 && wm;
        if (m) {
            const float* c = I1b + pix * CC;
#pragma unroll
            for (int ch = 0; ch < 3; ch++) {
                const float d = Iw[ch] - c[ch];
                DIb[pix * CC + ch] = d;
                const float u = d * 20.0f;
                const float rho = 0.005f * (sqrtf(fmaf(u, u, 1.0f)) - 1.0f);
                rho_s += (double)rho;
            }
            cnt_s += 3.0;
        } else {
            DIb[pix * CC + 0] = 0.0f;
            DIb[pix * CC + 1] = 0.0f;
            DIb[pix * CC + 2] = 0.0f;
        }
    }
#pragma unroll
    for (int off = 32; off >= 1; off >>= 1) {
        rho_s += __shfl_down(rho_s, off, 64);
        cnt_s += __shfl_down(cnt_s, off, 64);
    }
    __shared__ double wsum[BLK / 64][2];
    const int lane = tid & 63, wid = tid >> 6;
    if (lane == 0) { wsum[wid][0] = rho_s; wsum[wid][1] = cnt_s; }
    __syncthreads();
    if (tid < 2) {
        double s = 0.0;
#pragma unroll
        for (int w = 0; w < BLK / 64; w++) s += wsum[w][tid];
        fpart[((size_t)b * NTILES + tile) * 2 + tid] = s;
    }
}

extern "C" __global__ void k_finish(const double* __restrict__ p_fin,
                                    const double* __restrict__ fpart,
                                    float* __restrict__ out) {
    const int tid = threadIdx.x;  // 64 threads
    if (tid < BB * NPAR) out[tid] = (float)p_fin[tid];           // pf
    if (tid >= 48 && tid < 48 + BB) {
        const int b = tid - 48;
        double rs = 0.0, cs = 0.0;
        for (int t = 0; t < NTILES; t++) {
            rs += fpart[((size_t)b * NTILES + t) * 2 + 0];
            cs += fpart[((size_t)b * NTILES + t) * 2 + 1];
        }
        out[48 + b] = (float)(rs / fmax(cs, 1.0));               // err
    }
}

extern "C" void kernel_launch(void* const* d_in, const int* in_sizes, int n_in,
                              void* d_out, int out_size, void* d_ws, size_t ws_size,
                              hipStream_t stream) {
    const float* I1 = (const float*)d_in[0];
    const float* I2 = (const float*)d_in[1];
    const float* p0 = (const float*)d_in[2];
    float* out = (float*)d_out;

    // ws layout (all 8B-aligned):
    // [0)      p_store: (MAXIT+1)*8*6 doubles = 624  (4992 B)
    // [4992)   done:    (MAXIT+1)*8 ints      = 104  (416 B)
    // [5408)   partials: 8*128*24 doubles            (196608 B)
    // [202016) fpart:    8*128*2 doubles             (16384 B)
    double* p_store = (double*)d_ws;
    int* done_flags = (int*)((char*)d_ws + 4992);
    double* partials = (double*)((char*)d_ws + 5408);
    double* fpart = (double*)((char*)d_ws + 202016);

    dim3 grid(NTILES, BB), blk(BLK);
    k_init<<<1, 64, 0, stream>>>(p0, p_store, done_flags);
    for (int it = 0; it < MAXIT; it++) {
        k_warp_reduce<<<grid, blk, 0, stream>>>(I1, I2, p_store + (size_t)it * BB * NPAR,
                                                done_flags + it * BB, partials);
        k_solve<<<1, BLK, 0, stream>>>(partials, p_store + (size_t)it * BB * NPAR,
                                       done_flags + it * BB,
                                       p_store + (size_t)(it + 1) * BB * NPAR,
                                       done_flags + (it + 1) * BB);
    }
    float* DI_out = out + 56;
    float* Iw_out = out + 56 + (size_t)BB * HWPIX * CC;
    k_final_map<<<grid, blk, 0, stream>>>(I1, I2, p_store + (size_t)MAXIT * BB * NPAR,
                                          DI_out, Iw_out, fpart);
    k_finish<<<1, 64, 0, stream>>>(p_store + (size_t)MAXIT * BB * NPAR, fpart, out);
}

// Round 3
// 588.255 us; speedup vs baseline: 1.3329x; 1.3329x over previous
//
#include <hip/hip_runtime.h>
#include <math.h>

#define BB 8
#define HH 384
#define WW 384
#define CC 3
#define NPAR 6
#define DEL 10
#define MAXIT 12
#define NACC 24
#define HWPIX (HH*WW)           // 147456
#define NROWSV 364              // valid rows 10..373
#define SPANS 3
#define WTASKS (NROWSV*SPANS)   // 1092 wave-tasks per batch
#define WRBLK (WTASKS/4)        // 273 blocks of 4 waves
#define NTF 256                 // final-map tiles
#define TILEF (HWPIX/NTF)       // 576

typedef float vf4 __attribute__((ext_vector_type(4)));
typedef vf4 uvf4 __attribute__((aligned(4)));   // dword-aligned dwordx4 load is legal

__device__ __forceinline__ vf4 ldv4(const float* p) { return *(const uvf4*)p; }

__device__ __forceinline__ float cubicw(float s) {
    s = fabsf(s);
    float s2 = s * s, s3 = s2 * s;
    float w1 = 1.5f * s3 - 2.5f * s2 + 1.0f;
    float w2 = -0.5f * s3 + 2.5f * s2 - 4.0f * s + 2.0f;
    return (s <= 1.0f) ? w1 : ((s < 2.0f) ? w2 : 0.0f);
}

// bicubic sample of 3 channels at (xg,yg), clip-to-edge, Keys a=-0.5.
// Fast path (no clipping): 12 dwordx4 loads; slow path scalar fallback.
__device__ __forceinline__ void bicubic3(const float* __restrict__ Ib, double xg, double yg, float Iw[3]) {
    double fx = floor(xg), fy = floor(yg);
    float tx = (float)(xg - fx), ty = (float)(yg - fy);
    int xi = (int)fx;
    int yi = (int)fy;
    float wx[4], wyv[4];
#pragma unroll
    for (int k = 0; k < 4; k++) {
        wx[k]  = cubicw(tx - (float)(k - 1));
        wyv[k] = cubicw(ty - (float)(k - 1));
    }
    Iw[0] = 0.f; Iw[1] = 0.f; Iw[2] = 0.f;
    if (xi >= 1 && xi <= WW - 3 && yi >= 1 && yi <= HH - 3) {
        const float* base = Ib + (yi - 1) * (WW * CC) + (xi - 1) * CC;
#pragma unroll
        for (int j = 0; j < 4; j++) {
            const float* r = base + j * (WW * CC);
            vf4 v0 = ldv4(r), v1 = ldv4(r + 4), v2 = ldv4(r + 8);
            float r0 = fmaf(wx[0], v0.x, 0.f); r0 = fmaf(wx[1], v0.w, r0); r0 = fmaf(wx[2], v1.z, r0); r0 = fmaf(wx[3], v2.y, r0);
            float r1 = fmaf(wx[0], v0.y, 0.f); r1 = fmaf(wx[1], v1.x, r1); r1 = fmaf(wx[2], v1.w, r1); r1 = fmaf(wx[3], v2.z, r1);
            float r2 = fmaf(wx[0], v0.z, 0.f); r2 = fmaf(wx[1], v1.y, r2); r2 = fmaf(wx[2], v2.x, r2); r2 = fmaf(wx[3], v2.w, r2);
            Iw[0] = fmaf(wyv[j], r0, Iw[0]);
            Iw[1] = fmaf(wyv[j], r1, Iw[1]);
            Iw[2] = fmaf(wyv[j], r2, Iw[2]);
        }
    } else {
        int xx[4], yy[4];
#pragma unroll
        for (int k = 0; k < 4; k++) {
            xx[k] = min(max(xi + k - 1, 0), WW - 1);
            yy[k] = min(max(yi + k - 1, 0), HH - 1);
        }
#pragma unroll
        for (int j = 0; j < 4; j++) {
            const float* row = Ib + yy[j] * (WW * CC);
            float r0 = 0.f, r1 = 0.f, r2 = 0.f;
#pragma unroll
            for (int k = 0; k < 4; k++) {
                const float* q = row + xx[k] * CC;
                r0 = fmaf(wx[k], q[0], r0);
                r1 = fmaf(wx[k], q[1], r1);
                r2 = fmaf(wx[k], q[2], r2);
            }
            Iw[0] = fmaf(wyv[j], r0, Iw[0]);
            Iw[1] = fmaf(wyv[j], r1, Iw[1]);
            Iw[2] = fmaf(wyv[j], r2, Iw[2]);
        }
    }
}

extern "C" __global__ void k_init(const float* __restrict__ p0, double* __restrict__ p_store,
                                  int* __restrict__ done0) {
    int tid = threadIdx.x;
    if (tid < BB * NPAR) p_store[tid] = (double)p0[tid];
    if (tid < BB) done0[tid] = 0;
}

// One wave per (row, 1/3-row span). Y is wave-uniform -> only 13 fp64 accumulators.
extern "C" __global__ __launch_bounds__(256)
void k_warp_reduce(const float* __restrict__ I1, const float* __restrict__ I2,
                   const double* __restrict__ p_cur, const int* __restrict__ done_cur,
                   double* __restrict__ partials) {
    const int b = blockIdx.y;
    if (done_cur[b]) return;  // frozen batch: solve ignores stale partials
    const int tid = threadIdx.x;
    const int wid = tid >> 6, lane = tid & 63;
    const int wt = blockIdx.x * 4 + wid;      // 0..1091
    const int row = 10 + wt / 3;              // 10..373
    const int span = wt - (wt / 3) * 3;
    const int xstart = (span == 0) ? 10 : ((span == 1) ? 132 : 253);
    const int xend   = (span == 0) ? 132 : ((span == 1) ? 253 : 374);

    const double* p = p_cur + b * NPAR;
    const double M00 = 1.0 + p[2], M01 = p[3], M02 = p[0];
    const double M10 = p[4], M11 = 1.0 + p[5], M12 = p[1];
    const double Y = (double)row;
    const double Bx = M01 * Y + M02;
    const double By = M11 * Y + M12;
    const float* I1b = I1 + (size_t)b * HWPIX * CC;
    const float* I2b = I2 + (size_t)b * HWPIX * CC;

    double s[13];
#pragma unroll
    for (int i = 0; i < 13; i++) s[i] = 0.0;
    // s: 0=T0 1=T0X 2=T1 3=T1X 4=A 5=AX 6=AXX 7=B 8=BX 9=BXX 10=C 11=CX 12=CXX

    for (int x = xstart + lane; x < xend; x += 64) {
        const double X = (double)x;
        const double xg = fma(M00, X, Bx);
        const double yg = fma(M10, X, By);
        const double gx = rint(xg), gy = rint(yg);  // half-to-even like jnp.round
        if (!(gx >= (double)DEL && gx <= (double)(WW - DEL) &&
              gy >= (double)DEL && gy <= (double)(HH - DEL))) continue;      // wmask

        float Iw[3];
        bicubic3(I2b, xg, yg, Iw);

        const int pix = row * WW + x;
        const float* c = I1b + pix * CC;
        vf4 u0 = ldv4(c - 3);          // cl0 cl1 cl2 c0
        vf4 u1 = ldv4(c + 1);          // c1 c2 cr0 cr1
        float cr2 = c[5];
        vf4 uu = ldv4(c - WW * CC);    // cu0 cu1 cu2 .
        vf4 ud = ldv4(c + WW * CC);    // cd0 cd1 cd2 .

        const float cl[3] = {u0.x, u0.y, u0.z};
        const float cv[3] = {u0.w, u1.x, u1.y};
        const float cr[3] = {u1.z, u1.w, cr2};
        const float cu[3] = {uu.x, uu.y, uu.z};
        const float cd[3] = {ud.x, ud.y, ud.z};

        float Af = 0.f, Bf = 0.f, Cf = 0.f, T0f = 0.f, T1f = 0.f;
#pragma unroll
        for (int ch = 0; ch < 3; ch++) {
            const float Ix = (cr[ch] - cl[ch]) * 0.5f;
            const float Iy = (cd[ch] - cu[ch]) * 0.5f;
            const float d = Iw[ch] - cv[ch];
            const float u = d * 20.0f;                    // DI/LAM
            const float w = 1.0f / sqrtf(fmaf(u, u, 1.0f));
            const float wd = w * d;
            T0f = fmaf(Ix, wd, T0f);
            T1f = fmaf(Iy, wd, T1f);
            const float wIx = w * Ix;
            Af = fmaf(wIx, Ix, Af);
            Bf = fmaf(wIx, Iy, Bf);
            Cf = fmaf(w * Iy, Iy, Cf);
        }
        const double T0 = (double)T0f, T1 = (double)T1f;
        const double A = (double)Af, Bd = (double)Bf, Cd = (double)Cf;
        const double XX = X * X;
        s[0] += T0;  s[1] = fma(T0, X, s[1]);
        s[2] += T1;  s[3] = fma(T1, X, s[3]);
        s[4] += A;   s[5] = fma(A, X, s[5]);   s[6] = fma(A, XX, s[6]);
        s[7] += Bd;  s[8] = fma(Bd, X, s[8]);  s[9] = fma(Bd, XX, s[9]);
        s[10] += Cd; s[11] = fma(Cd, X, s[11]); s[12] = fma(Cd, XX, s[12]);
    }

    // wave shuffle reduce of the 13 sums (deterministic)
#pragma unroll
    for (int i = 0; i < 13; i++) {
        double v = s[i];
#pragma unroll
        for (int off = 32; off >= 1; off >>= 1) v += __shfl_down(v, off, 64);
        s[i] = v;
    }
    __shared__ double wacc[4][NACC];
    if (lane == 0) {
        const double YY = Y * Y;
        double* o = wacc[wid];
        o[0] = s[0];  o[1] = s[1];  o[2] = s[0] * Y;
        o[3] = s[2];  o[4] = s[3];  o[5] = s[2] * Y;
        o[6] = s[4];  o[7] = s[5];  o[8] = s[4] * Y;
        o[9] = s[6];  o[10] = s[5] * Y;  o[11] = s[4] * YY;
        o[12] = s[7]; o[13] = s[8]; o[14] = s[7] * Y;
        o[15] = s[9]; o[16] = s[8] * Y;  o[17] = s[7] * YY;
        o[18] = s[10]; o[19] = s[11]; o[20] = s[10] * Y;
        o[21] = s[12]; o[22] = s[11] * Y; o[23] = s[10] * YY;
    }
    __syncthreads();
    if (tid < NACC)
        partials[((size_t)b * WRBLK + blockIdx.x) * NACC + tid] =
            wacc[0][tid] + wacc[1][tid] + wacc[2][tid] + wacc[3][tid];
}

extern "C" __global__ __launch_bounds__(256)
void k_solve(const double* __restrict__ partials, const double* __restrict__ p_in,
             const int* __restrict__ done_in, double* __restrict__ p_out,
             int* __restrict__ done_out) {
    __shared__ double S[BB][NACC];
    const int tid = threadIdx.x;
    if (tid < BB * NACC) {
        const int b = tid / NACC, a = tid - b * NACC;
        const double* P = partials + (size_t)b * WRBLK * NACC + a;
        double s0 = 0.0, s1 = 0.0, s2 = 0.0, s3 = 0.0;
        int t = 0;
        for (; t + 3 < WRBLK; t += 4) {
            s0 += P[(size_t)(t + 0) * NACC];
            s1 += P[(size_t)(t + 1) * NACC];
            s2 += P[(size_t)(t + 2) * NACC];
            s3 += P[(size_t)(t + 3) * NACC];
        }
        for (; t < WRBLK; t++) s0 += P[(size_t)t * NACC];
        S[b][a] = (s0 + s1) + (s2 + s3);
    }
    __syncthreads();
    if (tid >= BB) return;
    const int b = tid;
    if (done_in[b]) {
        done_out[b] = 1;
        for (int i = 0; i < NPAR; i++) p_out[b * NPAR + i] = p_in[b * NPAR + i];
        return;
    }
    const double* Sb = S[b];
    // bvec: DIJ ordering [Ix, Iy, IxX, IxY, IyX, IyY]
    double bv[6] = {Sb[0], Sb[3], Sb[1], Sb[2], Sb[4], Sb[5]};
    double Hm[6][6];
    Hm[0][0] = Sb[6];  Hm[0][1] = Sb[12]; Hm[0][2] = Sb[7];  Hm[0][3] = Sb[8];  Hm[0][4] = Sb[13]; Hm[0][5] = Sb[14];
    Hm[1][1] = Sb[18]; Hm[1][2] = Sb[13]; Hm[1][3] = Sb[14]; Hm[1][4] = Sb[19]; Hm[1][5] = Sb[20];
    Hm[2][2] = Sb[9];  Hm[2][3] = Sb[10]; Hm[2][4] = Sb[15]; Hm[2][5] = Sb[16];
    Hm[3][3] = Sb[11]; Hm[3][4] = Sb[16]; Hm[3][5] = Sb[17];
    Hm[4][4] = Sb[21]; Hm[4][5] = Sb[22];
    Hm[5][5] = Sb[23];
    for (int i = 0; i < 6; i++)
        for (int jj = 0; jj < i; jj++) Hm[i][jj] = Hm[jj][i];
    for (int i = 0; i < 6; i++) Hm[i][i] += 1e-6;

    // 6x6 Gaussian elimination with partial pivoting (fp64)
    double Aa[6][7];
    for (int i = 0; i < 6; i++) {
        for (int jj = 0; jj < 6; jj++) Aa[i][jj] = Hm[i][jj];
        Aa[i][6] = bv[i];
    }
    for (int k = 0; k < 6; k++) {
        int piv = k;
        double mx = fabs(Aa[k][k]);
        for (int r = k + 1; r < 6; r++) {
            double v = fabs(Aa[r][k]);
            if (v > mx) { mx = v; piv = r; }
        }
        if (piv != k)
            for (int jj = k; jj < 7; jj++) { double t = Aa[k][jj]; Aa[k][jj] = Aa[piv][jj]; Aa[piv][jj] = t; }
        const double inv = 1.0 / Aa[k][k];
        for (int r = k + 1; r < 6; r++) {
            const double f = Aa[r][k] * inv;
            for (int jj = k; jj < 7; jj++) Aa[r][jj] -= f * Aa[k][jj];
        }
    }
    double dp[6];
    for (int i = 5; i >= 0; i--) {
        double sv = Aa[i][6];
        for (int jj = i + 1; jj < 6; jj++) sv -= Aa[i][jj] * dp[jj];
        dp[i] = sv / Aa[i][i];
    }
    const double nrm = sqrt(dp[0]*dp[0] + dp[1]*dp[1] + dp[2]*dp[2] + dp[3]*dp[3] + dp[4]*dp[4] + dp[5]*dp[5]);
    const int conv = (nrm < 1e-3) ? 1 : 0;

    // Mn = M(p) @ inv(M(dp));  affine 3x3, bottom row [0,0,1]
    const double* pc = p_in + b * NPAR;
    const double m00 = 1.0 + pc[2], m01 = pc[3], m02 = pc[0];
    const double m10 = pc[4], m11 = 1.0 + pc[5], m12 = pc[1];
    const double q00 = 1.0 + dp[2], q01 = dp[3], q02 = dp[0];
    const double q10 = dp[4], q11 = 1.0 + dp[5], q12 = dp[1];
    const double det = q00 * q11 - q01 * q10;
    const double i00 = q11 / det, i01 = -q01 / det;
    const double i10 = -q10 / det, i11 = q00 / det;
    const double it0 = -(i00 * q02 + i01 * q12);
    const double it1 = -(i10 * q02 + i11 * q12);
    const double n00 = m00 * i00 + m01 * i10;
    const double n01 = m00 * i01 + m01 * i11;
    const double n02 = m00 * it0 + m01 * it1 + m02;
    const double n10 = m10 * i00 + m11 * i10;
    const double n11 = m10 * i01 + m11 * i11;
    const double n12 = m10 * it0 + m11 * it1 + m12;
    p_out[b * NPAR + 0] = n02;
    p_out[b * NPAR + 1] = n12;
    p_out[b * NPAR + 2] = n00 - 1.0;
    p_out[b * NPAR + 3] = n01;
    p_out[b * NPAR + 4] = n10;
    p_out[b * NPAR + 5] = n11 - 1.0;
    done_out[b] = conv;
}

extern "C" __global__ __launch_bounds__(256)
void k_final_map(const float* __restrict__ I1, const float* __restrict__ I2,
                 const double* __restrict__ p_fin, float* __restrict__ DI_out,
                 float* __restrict__ Iw_out, double* __restrict__ fpart) {
    const int b = blockIdx.y;
    const int tile = blockIdx.x;
    const int tid = threadIdx.x;
    const double* p = p_fin + b * NPAR;
    const double M00 = 1.0 + p[2], M01 = p[3], M02 = p[0];
    const double M10 = p[4], M11 = 1.0 + p[5], M12 = p[1];
    const float* I1b = I1 + (size_t)b * HWPIX * CC;
    const float* I2b = I2 + (size_t)b * HWPIX * CC;
    float* DIb = DI_out + (size_t)b * HWPIX * CC;
    float* Iwb = Iw_out + (size_t)b * HWPIX * CC;

    double rho_s = 0.0, cnt_s = 0.0;
    const int pend = (tile + 1) * TILEF;
    for (int pix = tile * TILEF + tid; pix < pend; pix += 256) {
        const int y = pix / WW;
        const int x = pix - y * WW;
        const double xg = M00 * (double)x + M01 * (double)y + M02;
        const double yg = M10 * (double)x + M11 * (double)y + M12;
        float Iw[3];
        bicubic3(I2b, xg, yg, Iw);   // Iw written unmasked, all pixels
        Iwb[pix * CC + 0] = Iw[0];
        Iwb[pix * CC + 1] = Iw[1];
        Iwb[pix * CC + 2] = Iw[2];

        const bool v1 = (x >= DEL) && (x < WW - DEL) && (y >= DEL) && (y < HH - DEL);
        const double gx = rint(xg), gy = rint(yg);
        const bool wm = (gx >= (double)DEL && gx <= (double)(WW - DEL) &&
                         gy >= (double)DEL && gy <= (double)(HH - DEL));
        const bool m = v1 && wm;
        if (m) {
            const float* c = I1b + pix * CC;
#pragma unroll
            for (int ch = 0; ch < 3; ch++) {
                const float d = Iw[ch] - c[ch];
                DIb[pix * CC + ch] = d;
                const float u = d * 20.0f;
                const float rho = 0.005f * (sqrtf(fmaf(u, u, 1.0f)) - 1.0f);
                rho_s += (double)rho;
            }
            cnt_s += 3.0;
        } else {
            DIb[pix * CC + 0] = 0.0f;
            DIb[pix * CC + 1] = 0.0f;
            DIb[pix * CC + 2] = 0.0f;
        }
    }
#pragma unroll
    for (int off = 32; off >= 1; off >>= 1) {
        rho_s += __shfl_down(rho_s, off, 64);
        cnt_s += __shfl_down(cnt_s, off, 64);
    }
    __shared__ double wsum[4][2];
    const int lane = tid & 63, wid = tid >> 6;
    if (lane == 0) { wsum[wid][0] = rho_s; wsum[wid][1] = cnt_s; }
    __syncthreads();
    if (tid < 2) {
        double sv = wsum[0][tid] + wsum[1][tid] + wsum[2][tid] + wsum[3][tid];
        fpart[((size_t)b * NTF + tile) * 2 + tid] = sv;
    }
}

extern "C" __global__ __launch_bounds__(256)
void k_finish(const double* __restrict__ p_fin, const double* __restrict__ fpart,
              float* __restrict__ out) {
    __shared__ double rsum[BB][32], csum[BB][32];
    const int tid = threadIdx.x;  // 256 threads
    {
        const int b = tid >> 5, j = tid & 31;
        double rs = 0.0, cs = 0.0;
        for (int t = j; t < NTF; t += 32) {
            rs += fpart[((size_t)b * NTF + t) * 2 + 0];
            cs += fpart[((size_t)b * NTF + t) * 2 + 1];
        }
        rsum[b][j] = rs;
        csum[b][j] = cs;
    }
    __syncthreads();
    if (tid < BB * NPAR) out[tid] = (float)p_fin[tid];           // pf
    if (tid < BB) {
        double rs = 0.0, cs = 0.0;
        for (int j = 0; j < 32; j++) { rs += rsum[tid][j]; cs += csum[tid][j]; }
        out[48 + tid] = (float)(rs / fmax(cs, 1.0));             // err
    }
}

extern "C" void kernel_launch(void* const* d_in, const int* in_sizes, int n_in,
                              void* d_out, int out_size, void* d_ws, size_t ws_size,
                              hipStream_t stream) {
    const float* I1 = (const float*)d_in[0];
    const float* I2 = (const float*)d_in[1];
    const float* p0 = (const float*)d_in[2];
    float* out = (float*)d_out;

    // ws layout: p_store (MAXIT+1)*48 doubles (4992 B) | done (MAXIT+1)*8 ints (416 B)
    //            | fpart 8*256*2 doubles (32768 B)  -> 38176 B total
    double* p_store = (double*)d_ws;
    int* done_flags = (int*)((char*)d_ws + 4992);
    double* fpart = (double*)((char*)d_ws + 5408);
    // partials (8*273*24 doubles = 419 KB) live in d_out's DI region, which is
    // only written by k_final_map AFTER the last k_solve read. out+56 is 8B-aligned.
    double* partials = (double*)(out + 56);

    k_init<<<1, 64, 0, stream>>>(p0, p_store, done_flags);
    dim3 gridW(WRBLK, BB), blk(256);
    for (int it = 0; it < MAXIT; it++) {
        k_warp_reduce<<<gridW, blk, 0, stream>>>(I1, I2, p_store + (size_t)it * BB * NPAR,
                                                 done_flags + it * BB, partials);
        k_solve<<<1, blk, 0, stream>>>(partials, p_store + (size_t)it * BB * NPAR,
                                       done_flags + it * BB,
                                       p_store + (size_t)(it + 1) * BB * NPAR,
                                       done_flags + (it + 1) * BB);
    }
    float* DI_out = out + 56;
    float* Iw_out = out + 56 + (size_t)BB * HWPIX * CC;
    dim3 gridF(NTF, BB);
    k_final_map<<<gridF, blk, 0, stream>>>(I1, I2, p_store + (size_t)MAXIT * BB * NPAR,
                                           DI_out, Iw_out, fpart);
    k_finish<<<1, 256, 0, stream>>>(p_store + (size_t)MAXIT * BB * NPAR, fpart, out);
}

// Round 4
// 567.959 us; speedup vs baseline: 1.3806x; 1.0357x over previous
//
#include <hip/hip_runtime.h>
#include <math.h>

#define BB 8
#define HH 384
#define WW 384
#define CC 3
#define NPAR 6
#define DEL 10
#define MAXIT 12
#define NACC 24
#define HWPIX (HH*WW)           // 147456
#define NROWSV 364              // valid rows 10..373
#define SPANS 3
#define WTASKS (NROWSV*SPANS)   // 1092 wave-tasks per batch
#define WRBLK (WTASKS/4)        // 273 blocks of 4 waves
#define NTF 256                 // final-map tiles
#define TILEF (HWPIX/NTF)       // 576

typedef float vf4 __attribute__((ext_vector_type(4)));
typedef vf4 uvf4 __attribute__((aligned(4)));   // dword-aligned dwordx4 load is legal

__device__ __forceinline__ vf4 ldv4(const float* p) { return *(const uvf4*)p; }

__device__ __forceinline__ float cubicw(float s) {
    s = fabsf(s);
    float s2 = s * s, s3 = s2 * s;
    float w1 = 1.5f * s3 - 2.5f * s2 + 1.0f;
    float w2 = -0.5f * s3 + 2.5f * s2 - 4.0f * s + 2.0f;
    return (s <= 1.0f) ? w1 : ((s < 2.0f) ? w2 : 0.0f);
}

// fast-path-only bicubic (caller guarantees xi,yi in [1, W-3]/[1, H-3])
__device__ __forceinline__ void bicubic3_fast(const float* __restrict__ Ib, double xg, double yg, float Iw[3]) {
    double fx = floor(xg), fy = floor(yg);
    float tx = (float)(xg - fx), ty = (float)(yg - fy);
    int xi = (int)fx;
    int yi = (int)fy;
    float wx[4], wyv[4];
#pragma unroll
    for (int k = 0; k < 4; k++) {
        wx[k]  = cubicw(tx - (float)(k - 1));
        wyv[k] = cubicw(ty - (float)(k - 1));
    }
    Iw[0] = 0.f; Iw[1] = 0.f; Iw[2] = 0.f;
    const float* base = Ib + (yi - 1) * (WW * CC) + (xi - 1) * CC;
#pragma unroll
    for (int j = 0; j < 4; j++) {
        const float* r = base + j * (WW * CC);
        vf4 v0 = ldv4(r), v1 = ldv4(r + 4), v2 = ldv4(r + 8);
        float r0 = fmaf(wx[0], v0.x, 0.f); r0 = fmaf(wx[1], v0.w, r0); r0 = fmaf(wx[2], v1.z, r0); r0 = fmaf(wx[3], v2.y, r0);
        float r1 = fmaf(wx[0], v0.y, 0.f); r1 = fmaf(wx[1], v1.x, r1); r1 = fmaf(wx[2], v1.w, r1); r1 = fmaf(wx[3], v2.z, r1);
        float r2 = fmaf(wx[0], v0.z, 0.f); r2 = fmaf(wx[1], v1.y, r2); r2 = fmaf(wx[2], v2.x, r2); r2 = fmaf(wx[3], v2.w, r2);
        Iw[0] = fmaf(wyv[j], r0, Iw[0]);
        Iw[1] = fmaf(wyv[j], r1, Iw[1]);
        Iw[2] = fmaf(wyv[j], r2, Iw[2]);
    }
}

// general bicubic with clip-to-edge fallback (used by k_final_map only)
__device__ __forceinline__ void bicubic3(const float* __restrict__ Ib, double xg, double yg, float Iw[3]) {
    double fx = floor(xg), fy = floor(yg);
    int xi = (int)fx;
    int yi = (int)fy;
    if (xi >= 1 && xi <= WW - 3 && yi >= 1 && yi <= HH - 3) {
        bicubic3_fast(Ib, xg, yg, Iw);
        return;
    }
    float tx = (float)(xg - fx), ty = (float)(yg - fy);
    float wx[4], wyv[4];
    int xx[4], yy[4];
#pragma unroll
    for (int k = 0; k < 4; k++) {
        wx[k]  = cubicw(tx - (float)(k - 1));
        wyv[k] = cubicw(ty - (float)(k - 1));
        xx[k] = min(max(xi + k - 1, 0), WW - 1);
        yy[k] = min(max(yi + k - 1, 0), HH - 1);
    }
    Iw[0] = 0.f; Iw[1] = 0.f; Iw[2] = 0.f;
#pragma unroll
    for (int j = 0; j < 4; j++) {
        const float* row = Ib + yy[j] * (WW * CC);
        float r0 = 0.f, r1 = 0.f, r2 = 0.f;
#pragma unroll
        for (int k = 0; k < 4; k++) {
            const float* q = row + xx[k] * CC;
            r0 = fmaf(wx[k], q[0], r0);
            r1 = fmaf(wx[k], q[1], r1);
            r2 = fmaf(wx[k], q[2], r2);
        }
        Iw[0] = fmaf(wyv[j], r0, Iw[0]);
        Iw[1] = fmaf(wyv[j], r1, Iw[1]);
        Iw[2] = fmaf(wyv[j], r2, Iw[2]);
    }
}

// zero all atomic accumulators + init p/done, every call (ws is re-poisoned)
extern "C" __global__ __launch_bounds__(256)
void k_init(const float* __restrict__ p0, double* __restrict__ p_store,
            int* __restrict__ done0, double* __restrict__ S_all, double* __restrict__ Sf) {
    int tid = threadIdx.x;
    for (int i = tid; i < MAXIT * BB * NACC; i += 256) S_all[i] = 0.0;
    if (tid < 2 * BB) Sf[tid] = 0.0;
    if (tid < BB * NPAR) p_store[tid] = (double)p0[tid];
    if (tid < BB) done0[tid] = 0;
}

// One wave per (row, 1/3-row span). Y wave-uniform -> 13 fp64 accumulators.
// Branch-free inner body: always-fast bicubic, mask folded into robust weight.
extern "C" __global__ __launch_bounds__(256)
void k_warp_reduce(const float* __restrict__ I1, const float* __restrict__ I2,
                   const double* __restrict__ p_cur, const int* __restrict__ done_cur,
                   double* __restrict__ S) {
    const int b = blockIdx.y;
    if (done_cur[b]) return;  // frozen batch: S stays zero, solve copies p
    const int tid = threadIdx.x;
    const int wid = tid >> 6, lane = tid & 63;
    const int wt = blockIdx.x * 4 + wid;      // 0..1091
    const int row = 10 + wt / 3;              // 10..373
    const int span = wt - (wt / 3) * 3;
    const int xstart = (span == 0) ? 10 : ((span == 1) ? 132 : 253);
    const int xend   = (span == 0) ? 132 : ((span == 1) ? 253 : 374);

    const double* p = p_cur + b * NPAR;
    const double M00 = 1.0 + p[2], M01 = p[3], M02 = p[0];
    const double M10 = p[4], M11 = 1.0 + p[5], M12 = p[1];
    const double Y = (double)row;
    const double Bx = M01 * Y + M02;
    const double By = M11 * Y + M12;
    const float* I1b = I1 + (size_t)b * HWPIX * CC;
    const float* I2b = I2 + (size_t)b * HWPIX * CC;

    double s[13];
#pragma unroll
    for (int i = 0; i < 13; i++) s[i] = 0.0;
    // s: 0=T0 1=T0X 2=T1 3=T1X 4=A 5=AX 6=AXX 7=B 8=BX 9=BXX 10=C 11=CX 12=CXX

#pragma unroll
    for (int step = 0; step < 2; step++) {
        const int x = xstart + lane + 64 * step;       // x <= 380, memory-safe everywhere
        const double X = (double)x;
        const double xg = fma(M00, X, Bx);
        const double yg = fma(M10, X, By);
        const double gx = rint(xg), gy = rint(yg);     // half-to-even like jnp.round
        const bool ok = (x < xend) &&
                        (gx >= (double)DEL && gx <= (double)(WW - DEL) &&
                         gy >= (double)DEL && gy <= (double)(HH - DEL));
        // invalid lanes: force coords to a safe interior point (fast path, in-bounds)
        const double xs = ok ? xg : 100.0;
        const double ys = ok ? yg : 100.0;

        float Iw[3];
        bicubic3_fast(I2b, xs, ys, Iw);

        const int pix = row * WW + x;
        const float* c = I1b + pix * CC;
        vf4 u0 = ldv4(c - 3);          // cl0 cl1 cl2 c0
        vf4 u1 = ldv4(c + 1);          // c1 c2 cr0 cr1
        float cr2 = c[5];
        vf4 uu = ldv4(c - WW * CC);    // cu0 cu1 cu2 .
        vf4 ud = ldv4(c + WW * CC);    // cd0 cd1 cd2 .

        const float cl[3] = {u0.x, u0.y, u0.z};
        const float cv[3] = {u0.w, u1.x, u1.y};
        const float cr[3] = {u1.z, u1.w, cr2};
        const float cu[3] = {uu.x, uu.y, uu.z};
        const float cd[3] = {ud.x, ud.y, ud.z};

        const float msk = ok ? 1.0f : 0.0f;
        float Af = 0.f, Bf = 0.f, Cf = 0.f, T0f = 0.f, T1f = 0.f;
#pragma unroll
        for (int ch = 0; ch < 3; ch++) {
            const float Ix = (cr[ch] - cl[ch]) * 0.5f;
            const float Iy = (cd[ch] - cu[ch]) * 0.5f;
            const float d = Iw[ch] - cv[ch];
            const float u = d * 20.0f;                    // DI/LAM
            const float w = msk / sqrtf(fmaf(u, u, 1.0f));
            const float wd = w * d;
            T0f = fmaf(Ix, wd, T0f);
            T1f = fmaf(Iy, wd, T1f);
            const float wIx = w * Ix;
            Af = fmaf(wIx, Ix, Af);
            Bf = fmaf(wIx, Iy, Bf);
            Cf = fmaf(w * Iy, Iy, Cf);
        }
        const double T0 = (double)T0f, T1 = (double)T1f;
        const double A = (double)Af, Bd = (double)Bf, Cd = (double)Cf;
        const double XX = X * X;
        s[0] += T0;  s[1] = fma(T0, X, s[1]);
        s[2] += T1;  s[3] = fma(T1, X, s[3]);
        s[4] += A;   s[5] = fma(A, X, s[5]);   s[6] = fma(A, XX, s[6]);
        s[7] += Bd;  s[8] = fma(Bd, X, s[8]);  s[9] = fma(Bd, XX, s[9]);
        s[10] += Cd; s[11] = fma(Cd, X, s[11]); s[12] = fma(Cd, XX, s[12]);
    }

    // wave shuffle reduce of the 13 sums
#pragma unroll
    for (int i = 0; i < 13; i++) {
        double v = s[i];
#pragma unroll
        for (int off = 32; off >= 1; off >>= 1) v += __shfl_down(v, off, 64);
        s[i] = v;
    }
    __shared__ double wacc[4][NACC];
    if (lane == 0) {
        const double YY = Y * Y;
        double* o = wacc[wid];
        o[0] = s[0];  o[1] = s[1];  o[2] = s[0] * Y;
        o[3] = s[2];  o[4] = s[3];  o[5] = s[2] * Y;
        o[6] = s[4];  o[7] = s[5];  o[8] = s[4] * Y;
        o[9] = s[6];  o[10] = s[5] * Y;  o[11] = s[4] * YY;
        o[12] = s[7]; o[13] = s[8]; o[14] = s[7] * Y;
        o[15] = s[9]; o[16] = s[8] * Y;  o[17] = s[7] * YY;
        o[18] = s[10]; o[19] = s[11]; o[20] = s[10] * Y;
        o[21] = s[12]; o[22] = s[11] * Y; o[23] = s[10] * YY;
    }
    __syncthreads();
    if (tid < NACC) {
        double v = wacc[0][tid] + wacc[1][tid] + wacc[2][tid] + wacc[3][tid];
        unsafeAtomicAdd(&S[b * NACC + tid], v);   // hw f64 atomic; order noise ~1e-15
    }
}

extern "C" __global__ __launch_bounds__(256)
void k_solve(const double* __restrict__ S_it, const double* __restrict__ p_in,
             const int* __restrict__ done_in, double* __restrict__ p_out,
             int* __restrict__ done_out) {
    __shared__ double S[BB][NACC];
    const int tid = threadIdx.x;
    if (tid < BB * NACC) S[tid / NACC][tid % NACC] = S_it[tid];
    __syncthreads();
    if (tid >= BB) return;
    const int b = tid;
    if (done_in[b]) {
        done_out[b] = 1;
        for (int i = 0; i < NPAR; i++) p_out[b * NPAR + i] = p_in[b * NPAR + i];
        return;
    }
    const double* Sb = S[b];
    // bvec: DIJ ordering [Ix, Iy, IxX, IxY, IyX, IyY]
    double bv[6] = {Sb[0], Sb[3], Sb[1], Sb[2], Sb[4], Sb[5]};
    double Hm[6][6];
    Hm[0][0] = Sb[6];  Hm[0][1] = Sb[12]; Hm[0][2] = Sb[7];  Hm[0][3] = Sb[8];  Hm[0][4] = Sb[13]; Hm[0][5] = Sb[14];
    Hm[1][1] = Sb[18]; Hm[1][2] = Sb[13]; Hm[1][3] = Sb[14]; Hm[1][4] = Sb[19]; Hm[1][5] = Sb[20];
    Hm[2][2] = Sb[9];  Hm[2][3] = Sb[10]; Hm[2][4] = Sb[15]; Hm[2][5] = Sb[16];
    Hm[3][3] = Sb[11]; Hm[3][4] = Sb[16]; Hm[3][5] = Sb[17];
    Hm[4][4] = Sb[21]; Hm[4][5] = Sb[22];
    Hm[5][5] = Sb[23];
    for (int i = 0; i < 6; i++)
        for (int jj = 0; jj < i; jj++) Hm[i][jj] = Hm[jj][i];
    for (int i = 0; i < 6; i++) Hm[i][i] += 1e-6;

    double Aa[6][7];
    for (int i = 0; i < 6; i++) {
        for (int jj = 0; jj < 6; jj++) Aa[i][jj] = Hm[i][jj];
        Aa[i][6] = bv[i];
    }
    for (int k = 0; k < 6; k++) {
        int piv = k;
        double mx = fabs(Aa[k][k]);
        for (int r = k + 1; r < 6; r++) {
            double v = fabs(Aa[r][k]);
            if (v > mx) { mx = v; piv = r; }
        }
        if (piv != k)
            for (int jj = k; jj < 7; jj++) { double t = Aa[k][jj]; Aa[k][jj] = Aa[piv][jj]; Aa[piv][jj] = t; }
        const double inv = 1.0 / Aa[k][k];
        for (int r = k + 1; r < 6; r++) {
            const double f = Aa[r][k] * inv;
            for (int jj = k; jj < 7; jj++) Aa[r][jj] -= f * Aa[k][jj];
        }
    }
    double dp[6];
    for (int i = 5; i >= 0; i--) {
        double sv = Aa[i][6];
        for (int jj = i + 1; jj < 6; jj++) sv -= Aa[i][jj] * dp[jj];
        dp[i] = sv / Aa[i][i];
    }
    const double nrm = sqrt(dp[0]*dp[0] + dp[1]*dp[1] + dp[2]*dp[2] + dp[3]*dp[3] + dp[4]*dp[4] + dp[5]*dp[5]);
    const int conv = (nrm < 1e-3) ? 1 : 0;

    const double* pc = p_in + b * NPAR;
    const double m00 = 1.0 + pc[2], m01 = pc[3], m02 = pc[0];
    const double m10 = pc[4], m11 = 1.0 + pc[5], m12 = pc[1];
    const double q00 = 1.0 + dp[2], q01 = dp[3], q02 = dp[0];
    const double q10 = dp[4], q11 = 1.0 + dp[5], q12 = dp[1];
    const double det = q00 * q11 - q01 * q10;
    const double i00 = q11 / det, i01 = -q01 / det;
    const double i10 = -q10 / det, i11 = q00 / det;
    const double it0 = -(i00 * q02 + i01 * q12);
    const double it1 = -(i10 * q02 + i11 * q12);
    const double n00 = m00 * i00 + m01 * i10;
    const double n01 = m00 * i01 + m01 * i11;
    const double n02 = m00 * it0 + m01 * it1 + m02;
    const double n10 = m10 * i00 + m11 * i10;
    const double n11 = m10 * i01 + m11 * i11;
    const double n12 = m10 * it0 + m11 * it1 + m12;
    p_out[b * NPAR + 0] = n02;
    p_out[b * NPAR + 1] = n12;
    p_out[b * NPAR + 2] = n00 - 1.0;
    p_out[b * NPAR + 3] = n01;
    p_out[b * NPAR + 4] = n10;
    p_out[b * NPAR + 5] = n11 - 1.0;
    done_out[b] = conv;
}

extern "C" __global__ __launch_bounds__(256)
void k_final_map(const float* __restrict__ I1, const float* __restrict__ I2,
                 const double* __restrict__ p_fin, float* __restrict__ DI_out,
                 float* __restrict__ Iw_out, double* __restrict__ Sf) {
    const int b = blockIdx.y;
    const int tile = blockIdx.x;
    const int tid = threadIdx.x;
    const double* p = p_fin + b * NPAR;
    const double M00 = 1.0 + p[2], M01 = p[3], M02 = p[0];
    const double M10 = p[4], M11 = 1.0 + p[5], M12 = p[1];
    const float* I1b = I1 + (size_t)b * HWPIX * CC;
    const float* I2b = I2 + (size_t)b * HWPIX * CC;
    float* DIb = DI_out + (size_t)b * HWPIX * CC;
    float* Iwb = Iw_out + (size_t)b * HWPIX * CC;

    double rho_s = 0.0, cnt_s = 0.0;
    const int pend = (tile + 1) * TILEF;
    for (int pix = tile * TILEF + tid; pix < pend; pix += 256) {
        const int y = pix / WW;
        const int x = pix - y * WW;
        const double xg = M00 * (double)x + M01 * (double)y + M02;
        const double yg = M10 * (double)x + M11 * (double)y + M12;
        float Iw[3];
        bicubic3(I2b, xg, yg, Iw);   // Iw written unmasked, all pixels
        Iwb[pix * CC + 0] = Iw[0];
        Iwb[pix * CC + 1] = Iw[1];
        Iwb[pix * CC + 2] = Iw[2];

        const bool v1 = (x >= DEL) && (x < WW - DEL) && (y >= DEL) && (y < HH - DEL);
        const double gx = rint(xg), gy = rint(yg);
        const bool wm = (gx >= (double)DEL && gx <= (double)(WW - DEL) &&
                         gy >= (double)DEL && gy <= (double)(HH - DEL));
        const bool m = v1 && wm;
        if (m) {
            const float* c = I1b + pix * CC;
#pragma unroll
            for (int ch = 0; ch < 3; ch++) {
                const float d = Iw[ch] - c[ch];
                DIb[pix * CC + ch] = d;
                const float u = d * 20.0f;
                const float rho = 0.005f * (sqrtf(fmaf(u, u, 1.0f)) - 1.0f);
                rho_s += (double)rho;
            }
            cnt_s += 3.0;
        } else {
            DIb[pix * CC + 0] = 0.0f;
            DIb[pix * CC + 1] = 0.0f;
            DIb[pix * CC + 2] = 0.0f;
        }
    }
#pragma unroll
    for (int off = 32; off >= 1; off >>= 1) {
        rho_s += __shfl_down(rho_s, off, 64);
        cnt_s += __shfl_down(cnt_s, off, 64);
    }
    __shared__ double wsum[4][2];
    const int lane = tid & 63, wid = tid >> 6;
    if (lane == 0) { wsum[wid][0] = rho_s; wsum[wid][1] = cnt_s; }
    __syncthreads();
    if (tid < 2) {
        double sv = wsum[0][tid] + wsum[1][tid] + wsum[2][tid] + wsum[3][tid];
        unsafeAtomicAdd(&Sf[b * 2 + tid], sv);
    }
}

extern "C" __global__ void k_finish(const double* __restrict__ p_fin,
                                    const double* __restrict__ Sf,
                                    float* __restrict__ out) {
    const int tid = threadIdx.x;  // 64 threads
    if (tid < BB * NPAR) out[tid] = (float)p_fin[tid];           // pf
    if (tid >= 48 && tid < 48 + BB) {
        const int b = tid - 48;
        out[48 + b] = (float)(Sf[b * 2 + 0] / fmax(Sf[b * 2 + 1], 1.0));  // err
    }
}

extern "C" void kernel_launch(void* const* d_in, const int* in_sizes, int n_in,
                              void* d_out, int out_size, void* d_ws, size_t ws_size,
                              hipStream_t stream) {
    const float* I1 = (const float*)d_in[0];
    const float* I2 = (const float*)d_in[1];
    const float* p0 = (const float*)d_in[2];
    float* out = (float*)d_out;

    // ws layout (8B-aligned):
    // [0)      p_store  (MAXIT+1)*48 doubles   = 4992 B
    // [4992)   done     (MAXIT+1)*8 ints       = 416 B
    // [5408)   S_all    MAXIT*8*24 doubles     = 18432 B
    // [23840)  Sf       16 doubles             = 128 B
    double* p_store = (double*)d_ws;
    int* done_flags = (int*)((char*)d_ws + 4992);
    double* S_all = (double*)((char*)d_ws + 5408);
    double* Sf = (double*)((char*)d_ws + 23840);

    dim3 blk(256);
    k_init<<<1, blk, 0, stream>>>(p0, p_store, done_flags, S_all, Sf);
    dim3 gridW(WRBLK, BB);
    for (int it = 0; it < MAXIT; it++) {
        double* S_it = S_all + (size_t)it * BB * NACC;
        k_warp_reduce<<<gridW, blk, 0, stream>>>(I1, I2, p_store + (size_t)it * BB * NPAR,
                                                 done_flags + it * BB, S_it);
        k_solve<<<1, blk, 0, stream>>>(S_it, p_store + (size_t)it * BB * NPAR,
                                       done_flags + it * BB,
                                       p_store + (size_t)(it + 1) * BB * NPAR,
                                       done_flags + (it + 1) * BB);
    }
    float* DI_out = out + 56;
    float* Iw_out = out + 56 + (size_t)BB * HWPIX * CC;
    dim3 gridF(NTF, BB);
    k_final_map<<<gridF, blk, 0, stream>>>(I1, I2, p_store + (size_t)MAXIT * BB * NPAR,
                                           DI_out, Iw_out, Sf);
    k_finish<<<1, 64, 0, stream>>>(p_store + (size_t)MAXIT * BB * NPAR, Sf, out);
}